// Round 9
// baseline (49586.230 us; speedup 1.0000x reference)
//
#include <hip/hip_runtime.h>
#include <hip/hip_bf16.h>
#include <cstdint>
#include <cstddef>

#define TSEQ 2048
#define BB   32
#define UU   512
#define NCOL 1536
#define GB   32      // blocks per group
#define RING 8       // h1 ring depth

static __device__ __forceinline__ float aload(const float* p) {
    return __int_as_float(__hip_atomic_load((const int*)p, __ATOMIC_RELAXED,
                                            __HIP_MEMORY_SCOPE_AGENT));
}
static __device__ __forceinline__ void astore(float* p, float v) {
    __hip_atomic_store((int*)p, __float_as_int(v), __ATOMIC_RELAXED,
                       __HIP_MEMORY_SCOPE_AGENT);
}
static __device__ __forceinline__ unsigned f2bfu(float f) {
    __hip_bfloat16 b = __float2bfloat16(f);
    unsigned short s;
    __builtin_memcpy(&s, &b, 2);
    return (unsigned)s;
}
static __device__ __forceinline__ float bflo(unsigned u) { return __uint_as_float(u << 16); }
static __device__ __forceinline__ float bfhi(unsigned u) { return __uint_as_float(u & 0xffff0000u); }
static __device__ __forceinline__ int swz512(int k) { return k ^ (((k >> 6) & 7) << 2); }

// ---- repetition macros: force literal-constant private-array indices ------
#define REP4(X, B)  X(B) X((B)+1) X((B)+2) X((B)+3)
#define REP16(X, B) REP4(X, B) REP4(X, (B)+4) REP4(X, (B)+8) REP4(X, (B)+12)
#define REP32(X)    REP16(X, 0) REP16(X, 16)
#define REPQ_LO(X)  X(0) X(4) X(8) X(12) X(16) X(20) X(24) X(28)
#define REPQ_HI(X)  X(32) X(36) X(40) X(44) X(48) X(52) X(56) X(60)
#define REPQ_ALL(X) REPQ_LO(X) REPQ_HI(X)

// ---------------------------------------------------------------------------
// fp32 GEMM for xp1 = x@k1 + b_in  (proven R3 kernel)
// ---------------------------------------------------------------------------
__global__ __launch_bounds__(256)
void gemm_bias(const float* __restrict__ A, const float* __restrict__ W,
               const float* __restrict__ bias, float* __restrict__ C,
               int M, int N, int K)
{
    __shared__ float As[16][68];
    __shared__ float Bs[16][64];

    const int tid = threadIdx.x;
    const int tx = tid & 15, ty = tid >> 4;
    const int m0 = blockIdx.y * 64, n0 = blockIdx.x * 64;

    float acc[4][4] = {};

    for (int k0 = 0; k0 < K; k0 += 16) {
        {
            int r  = tid >> 2;
            int kq = (tid & 3) * 4;
            float4 av = *(const float4*)&A[(size_t)(m0 + r) * K + k0 + kq];
            As[kq + 0][r] = av.x;
            As[kq + 1][r] = av.y;
            As[kq + 2][r] = av.z;
            As[kq + 3][r] = av.w;
        }
        {
            int kk = tid >> 4;
            int n  = (tid & 15) * 4;
            *(float4*)&Bs[kk][n] = *(const float4*)&W[(size_t)(k0 + kk) * N + n0 + n];
        }
        __syncthreads();

        #pragma unroll
        for (int kk = 0; kk < 16; ++kk) {
            float av0 = As[kk][ty * 4 + 0];
            float av1 = As[kk][ty * 4 + 1];
            float av2 = As[kk][ty * 4 + 2];
            float av3 = As[kk][ty * 4 + 3];
            float4 bv = *(const float4*)&Bs[kk][tx * 4];
            acc[0][0] = fmaf(av0, bv.x, acc[0][0]);
            acc[0][1] = fmaf(av0, bv.y, acc[0][1]);
            acc[0][2] = fmaf(av0, bv.z, acc[0][2]);
            acc[0][3] = fmaf(av0, bv.w, acc[0][3]);
            acc[1][0] = fmaf(av1, bv.x, acc[1][0]);
            acc[1][1] = fmaf(av1, bv.y, acc[1][1]);
            acc[1][2] = fmaf(av1, bv.z, acc[1][2]);
            acc[1][3] = fmaf(av1, bv.w, acc[1][3]);
            acc[2][0] = fmaf(av2, bv.x, acc[2][0]);
            acc[2][1] = fmaf(av2, bv.y, acc[2][1]);
            acc[2][2] = fmaf(av2, bv.z, acc[2][2]);
            acc[2][3] = fmaf(av2, bv.w, acc[2][3]);
            acc[3][0] = fmaf(av3, bv.x, acc[3][0]);
            acc[3][1] = fmaf(av3, bv.y, acc[3][1]);
            acc[3][2] = fmaf(av3, bv.z, acc[3][2]);
            acc[3][3] = fmaf(av3, bv.w, acc[3][3]);
        }
        __syncthreads();
    }

    float4 bb = *(const float4*)&bias[n0 + tx * 4];
    #pragma unroll
    for (int i = 0; i < 4; ++i) {
        float4 v;
        v.x = acc[i][0] + bb.x;
        v.y = acc[i][1] + bb.y;
        v.z = acc[i][2] + bb.z;
        v.w = acc[i][3] + bb.w;
        *(float4*)&C[(size_t)(m0 + ty * 4 + i) * N + n0 + tx * 4] = v;
    }
}

// ---------------------------------------------------------------------------
// Fused 2-layer GRU, one 1024-thread block per (group,slot): tid<512 = role A
// (layer 1, step i), tid>=512 = role C (layer 2, step i-1). Grid = 256 blocks
// = 1 block/CU. waves_per_eu(4,4) -> 128-VGPR budget for the 16-wave block.
// ALL private weight-array accesses are macro-expanded with literal indices
// (R4-R8 lesson: big inner loops defeat the unroller -> runtime indices ->
// arrays demoted to scratch -> ~100 GB/dispatch re-read; rocprof signature:
// VGPR_Count=64 + FETCH_SIZE 1e8 KB).
// Cross-block exchange via RELAXED AGENT atomics (no fences); __syncthreads()
// drains vmcnt before flag posts. Deps per iteration i:
//   A@i  <- {group A @ i-1 (aflags>=i)}
//   C@i-1<- {group C @ i-2 (cflags>=i-1), group A @ i-1 (aflags>=i)}
// Group drift < 2 iterations -> ring depth 8 is ample.
// ---------------------------------------------------------------------------
__global__ __attribute__((amdgpu_waves_per_eu(4, 4))) __launch_bounds__(1024)
void gru_fused(const float* __restrict__ xp1,  const float* __restrict__ h0,
               const float* __restrict__ rk1,  const float* __restrict__ b1,
               const float* __restrict__ k2,   const float* __restrict__ rk2,
               const float* __restrict__ b2,
               float* h1ring,                 // [RING][BB][UU]
               float* hp2,                    // [2][BB][UU]
               int* aflags, int* cflags,      // [256] each, zeroed
               float* __restrict__ out2, float* __restrict__ state1,
               float* __restrict__ state2)
{
    __shared__ float hl1[4][512];        // h1[i-1] (shared by A and C)
    __shared__ float hl2[4][512];        // h2[i-2] (C)
    __shared__ float xp[2][192];         // xp1 slices (A), dbuf
    __shared__ float innRA[48][4];
    __shared__ float innRC[48][4];
    __shared__ float innXC[48][4];
    __shared__ unsigned wl2[384 * 17];   // C: rk2 k=0..31, per-thread chunks

    const int tid  = threadIdx.x;
    const int lb   = blockIdx.x;               // 0..255
    const int g    = lb & 7, slot = lb >> 3;
    const int u0   = slot * 16, b0 = g * 4;
    const bool isA = (tid < 512);
    const int ht   = isA ? tid : (tid - 512);  // half-tid 0..511
    const int hc   = ht >> 3, hj = ht & 7;
    const int jsw  = hj << 2;
    const int col  = (hc < 48) ? ((hc >> 4) * UU + u0 + (hc & 15)) : 0;
    const int wlbase = ht * 17;

    // ---- weights (literal-index macro expansion everywhere) ----
    unsigned wMain[32];   // A: rk1 slice ; C: k2 slice (bf16-packed)
    unsigned wHi[16];     // C only: rk2 k=32..63
    if (hc < 48) {
        if (isA) {
            const float* rbW = rk1 + (size_t)(hj * 64) * NCOL + col;
#define LWMAIN(M) wMain[(M)] = f2bfu(rbW[(size_t)(2*(M)) * NCOL]) \
                           | (f2bfu(rbW[(size_t)(2*(M)+1) * NCOL]) << 16);
            REP32(LWMAIN)
        } else {
            const float* rbW = k2  + (size_t)(hj * 64) * NCOL + col;
            const float* rbR = rk2 + (size_t)(hj * 64) * NCOL + col;
            REP32(LWMAIN)
#undef LWMAIN
#define LWRLO(M) wl2[wlbase + (M)] = f2bfu(rbR[(size_t)(2*(M)) * NCOL]) \
                                 | (f2bfu(rbR[(size_t)(2*(M)+1) * NCOL]) << 16);
#define LWRHI(M) wHi[(M)] = f2bfu(rbR[(size_t)(32+2*(M)) * NCOL]) \
                        | (f2bfu(rbR[(size_t)(33+2*(M)) * NCOL]) << 16);
            REP16(LWRLO, 0)
            REP16(LWRHI, 0)
        }
    }

    // ---- biases ----
    float bz = 0, brr = 0, bh = 0, b2z = 0, b2r = 0, b2h = 0;
    if (ht < 64) {
        int iu = ht & 15;
        if (isA) {
            bz  = b1[NCOL + u0 + iu];
            brr = b1[NCOL + UU + u0 + iu];
            bh  = b1[NCOL + 2 * UU + u0 + iu];
        } else {
            bz  = b2[NCOL + u0 + iu];
            brr = b2[NCOL + UU + u0 + iu];
            bh  = b2[NCOL + 2 * UU + u0 + iu];
            b2z = b2[u0 + iu];
            b2r = b2[UU + u0 + iu];
            b2h = b2[2 * UU + u0 + iu];
        }
    }

    // ---- prefill xp[0] with t=0 slice (A threads 384..511) ----
    if (isA && ht >= 384) {
        int p = ht - 384;
        {
            int cc = p >> 2, b = p & 3;
            xp[0][p] = xp1[((size_t)(b0 + b) * TSEQ + 0) * NCOL
                           + (cc >> 4) * UU + u0 + (cc & 15)];
        }
        int p2 = p + 128;
        if (p2 < 192) {
            int cc = p2 >> 2, b = p2 & 3;
            xp[0][p2] = xp1[((size_t)(b0 + b) * TSEQ + 0) * NCOL
                            + (cc >> 4) * UU + u0 + (cc & 15)];
        }
    }
    __syncthreads();

    for (int i = 0; i <= TSEQ; ++i) {
        // ---- poll phase ----
        if (i > 0) {
            if (isA) {
                if (ht < 64 && i < TSEQ) {
                    const int* fp = &aflags[g * GB + (ht & 31)];
                    while (!__all(__hip_atomic_load(fp, __ATOMIC_RELAXED,
                                  __HIP_MEMORY_SCOPE_AGENT) >= i)) {}
                }
            } else if (ht < 64) {
                const int thr = (ht < 32) ? (i - 1) : i;
                const int* fp = (ht < 32) ? &cflags[g * GB + ht]
                                          : &aflags[g * GB + (ht - 32)];
                while (!__all(__hip_atomic_load(fp, __ATOMIC_RELAXED,
                              __HIP_MEMORY_SCOPE_AGENT) >= thr)) {}
            }
        }
        __syncthreads();

        // ---- stage hl1 <- h1[i-1] (h0 at i==0); all 1024 threads ----
        {
            const float* hs = (i == 0) ? h0
                            : (h1ring + (size_t)((i - 1) & 7) * BB * UU);
            #pragma unroll
            for (int q = 0; q < 2; ++q) {
                int idx = q * 1024 + tid;
                int row = idx >> 9, k = idx & 511;
                float v = (i == 0) ? hs[(size_t)(b0 + row) * UU + k]
                                   : aload(&hs[(size_t)(b0 + row) * UU + k]);
                hl1[row][swz512(k)] = v;
            }
        }
        // ---- stage hl2 <- h2[i-2] (h0 at i==1); C half ----
        if (!isA && i >= 1) {
            const float* hs2 = hp2 + (size_t)(i & 1) * BB * UU;
            #pragma unroll
            for (int q = 0; q < 4; ++q) {
                int idx = q * 512 + ht;
                int row = idx >> 9, k = idx & 511;
                float v = (i == 1) ? h0[(size_t)(b0 + row) * UU + k]
                                   : aload(&hs2[(size_t)(b0 + row) * UU + k]);
                hl2[row][swz512(k)] = v;
            }
        }
        __syncthreads();

        // ---- work phase ----
        if (isA) {
            if (i < TSEQ) {
                if (hc < 48) {
                    float a0 = 0, a1 = 0, a2 = 0, a3 = 0;
                    const int kb = hj * 64;
#define STEPA(Q) { \
    const int p_ = kb + ((Q) ^ jsw); \
    float4 v0 = *(const float4*)&hl1[0][p_]; \
    float4 v1 = *(const float4*)&hl1[1][p_]; \
    float4 v2 = *(const float4*)&hl1[2][p_]; \
    float4 v3 = *(const float4*)&hl1[3][p_]; \
    unsigned wa = wMain[(Q) >> 1], wb_ = wMain[((Q) >> 1) + 1]; \
    float w0 = bflo(wa), w1 = bfhi(wa), w2 = bflo(wb_), w3 = bfhi(wb_); \
    a0 = fmaf(w0, v0.x, a0); a1 = fmaf(w0, v1.x, a1); \
    a2 = fmaf(w0, v2.x, a2); a3 = fmaf(w0, v3.x, a3); \
    a0 = fmaf(w1, v0.y, a0); a1 = fmaf(w1, v1.y, a1); \
    a2 = fmaf(w1, v2.y, a2); a3 = fmaf(w1, v3.y, a3); \
    a0 = fmaf(w2, v0.z, a0); a1 = fmaf(w2, v1.z, a1); \
    a2 = fmaf(w2, v2.z, a2); a3 = fmaf(w2, v3.z, a3); \
    a0 = fmaf(w3, v0.w, a0); a1 = fmaf(w3, v1.w, a1); \
    a2 = fmaf(w3, v2.w, a2); a3 = fmaf(w3, v3.w, a3); }
                    REPQ_ALL(STEPA)
                    #pragma unroll
                    for (int m = 1; m < 8; m <<= 1) {
                        a0 += __shfl_xor(a0, m); a1 += __shfl_xor(a1, m);
                        a2 += __shfl_xor(a2, m); a3 += __shfl_xor(a3, m);
                    }
                    if (hj == 0) {
                        innRA[hc][0] = a0; innRA[hc][1] = a1;
                        innRA[hc][2] = a2; innRA[hc][3] = a3;
                    }
                } else if (ht >= 384 && i + 1 < TSEQ) {   // prefetch xp1[i+1]
                    int p = ht - 384, nb = (i + 1) & 1;
                    {
                        int cc = p >> 2, b = p & 3;
                        xp[nb][p] = xp1[((size_t)(b0 + b) * TSEQ + (i + 1)) * NCOL
                                        + (cc >> 4) * UU + u0 + (cc & 15)];
                    }
                    int p2 = p + 128;
                    if (p2 < 192) {
                        int cc = p2 >> 2, b = p2 & 3;
                        xp[nb][p2] = xp1[((size_t)(b0 + b) * TSEQ + (i + 1)) * NCOL
                                         + (cc >> 4) * UU + u0 + (cc & 15)];
                    }
                }
            }
        } else if (i >= 1 && hc < 48) {
            const int kb = hj * 64;
            float a0 = 0, a1 = 0, a2 = 0, a3 = 0;
            float x0 = 0, x1 = 0, x2 = 0, x3 = 0;
            // R-pass k=0..31: rk2 from LDS chunks (literal offsets)
#define STEPR_LDS(Q) { \
    const int p_ = kb + ((Q) ^ jsw); \
    float4 v0 = *(const float4*)&hl2[0][p_]; \
    float4 v1 = *(const float4*)&hl2[1][p_]; \
    float4 v2 = *(const float4*)&hl2[2][p_]; \
    float4 v3 = *(const float4*)&hl2[3][p_]; \
    unsigned wa = wl2[wlbase + ((Q) >> 1)], wb_ = wl2[wlbase + ((Q) >> 1) + 1]; \
    float w0 = bflo(wa), w1 = bfhi(wa), w2 = bflo(wb_), w3 = bfhi(wb_); \
    a0 = fmaf(w0, v0.x, a0); a1 = fmaf(w0, v1.x, a1); \
    a2 = fmaf(w0, v2.x, a2); a3 = fmaf(w0, v3.x, a3); \
    a0 = fmaf(w1, v0.y, a0); a1 = fmaf(w1, v1.y, a1); \
    a2 = fmaf(w1, v2.y, a2); a3 = fmaf(w1, v3.y, a3); \
    a0 = fmaf(w2, v0.z, a0); a1 = fmaf(w2, v1.z, a1); \
    a2 = fmaf(w2, v2.z, a2); a3 = fmaf(w2, v3.z, a3); \
    a0 = fmaf(w3, v0.w, a0); a1 = fmaf(w3, v1.w, a1); \
    a2 = fmaf(w3, v2.w, a2); a3 = fmaf(w3, v3.w, a3); }
            REPQ_LO(STEPR_LDS)
            // R-pass k=32..63: rk2 from registers (literal indices)
#define STEPR_REG(Q) { \
    const int p_ = kb + ((Q) ^ jsw); \
    float4 v0 = *(const float4*)&hl2[0][p_]; \
    float4 v1 = *(const float4*)&hl2[1][p_]; \
    float4 v2 = *(const float4*)&hl2[2][p_]; \
    float4 v3 = *(const float4*)&hl2[3][p_]; \
    unsigned wa = wHi[((Q) - 32) >> 1], wb_ = wHi[(((Q) - 32) >> 1) + 1]; \
    float w0 = bflo(wa), w1 = bfhi(wa), w2 = bflo(wb_), w3 = bfhi(wb_); \
    a0 = fmaf(w0, v0.x, a0); a1 = fmaf(w0, v1.x, a1); \
    a2 = fmaf(w0, v2.x, a2); a3 = fmaf(w0, v3.x, a3); \
    a0 = fmaf(w1, v0.y, a0); a1 = fmaf(w1, v1.y, a1); \
    a2 = fmaf(w1, v2.y, a2); a3 = fmaf(w1, v3.y, a3); \
    a0 = fmaf(w2, v0.z, a0); a1 = fmaf(w2, v1.z, a1); \
    a2 = fmaf(w2, v2.z, a2); a3 = fmaf(w2, v3.z, a3); \
    a0 = fmaf(w3, v0.w, a0); a1 = fmaf(w3, v1.w, a1); \
    a2 = fmaf(w3, v2.w, a2); a3 = fmaf(w3, v3.w, a3); }
            REPQ_HI(STEPR_REG)
            // X-pass: k2 (regs) x h1
#define STEPX(Q) { \
    const int p_ = kb + ((Q) ^ jsw); \
    float4 v0 = *(const float4*)&hl1[0][p_]; \
    float4 v1 = *(const float4*)&hl1[1][p_]; \
    float4 v2 = *(const float4*)&hl1[2][p_]; \
    float4 v3 = *(const float4*)&hl1[3][p_]; \
    unsigned wa = wMain[(Q) >> 1], wb_ = wMain[((Q) >> 1) + 1]; \
    float w0 = bflo(wa), w1 = bfhi(wa), w2 = bflo(wb_), w3 = bfhi(wb_); \
    x0 = fmaf(w0, v0.x, x0); x1 = fmaf(w0, v1.x, x1); \
    x2 = fmaf(w0, v2.x, x2); x3 = fmaf(w0, v3.x, x3); \
    x0 = fmaf(w1, v0.y, x0); x1 = fmaf(w1, v1.y, x1); \
    x2 = fmaf(w1, v2.y, x2); x3 = fmaf(w1, v3.y, x3); \
    x0 = fmaf(w2, v0.z, x0); x1 = fmaf(w2, v1.z, x1); \
    x2 = fmaf(w2, v2.z, x2); x3 = fmaf(w2, v3.z, x3); \
    x0 = fmaf(w3, v0.w, x0); x1 = fmaf(w3, v1.w, x1); \
    x2 = fmaf(w3, v2.w, x2); x3 = fmaf(w3, v3.w, x3); }
            REPQ_ALL(STEPX)
            #pragma unroll
            for (int m = 1; m < 8; m <<= 1) {
                a0 += __shfl_xor(a0, m); a1 += __shfl_xor(a1, m);
                a2 += __shfl_xor(a2, m); a3 += __shfl_xor(a3, m);
                x0 += __shfl_xor(x0, m); x1 += __shfl_xor(x1, m);
                x2 += __shfl_xor(x2, m); x3 += __shfl_xor(x3, m);
            }
            if (hj == 0) {
                innRC[hc][0] = a0; innRC[hc][1] = a1;
                innRC[hc][2] = a2; innRC[hc][3] = a3;
                innXC[hc][0] = x0; innXC[hc][1] = x1;
                innXC[hc][2] = x2; innXC[hc][3] = x3;
            }
        }
        __syncthreads();

        // ---- gates ----
        if (isA) {
            if (i < TSEQ && ht < 64) {
                int bl = ht >> 4, iu = ht & 15, ug = u0 + iu;
                float rz = innRA[iu][bl]      + bz;
                float rr = innRA[16 + iu][bl] + brr;
                float rh = innRA[32 + iu][bl] + bh;
                const float* xv = xp[i & 1];
                float xz = xv[iu * 4 + bl];
                float xr = xv[(16 + iu) * 4 + bl];
                float xh = xv[(32 + iu) * 4 + bl];
                float z  = 1.f / (1.f + expf(-(xz + rz)));
                float r  = 1.f / (1.f + expf(-(xr + rr)));
                float hh = tanhf(xh + r * rh);
                float hold = hl1[bl][swz512(ug)];
                float hnew = z * hold + (1.f - z) * hh;
                astore(h1ring + (size_t)(i & 7) * BB * UU
                              + (size_t)(b0 + bl) * UU + ug, hnew);
                if (i == TSEQ - 1) state1[(size_t)(b0 + bl) * UU + ug] = hnew;
            }
        } else if (i >= 1 && ht < 64) {
            int tc = i - 1;
            int bl = ht >> 4, iu = ht & 15, ug = u0 + iu;
            float rz = innRC[iu][bl]      + bz;
            float rr = innRC[16 + iu][bl] + brr;
            float rh = innRC[32 + iu][bl] + bh;
            float xz = innXC[iu][bl]      + b2z;
            float xr = innXC[16 + iu][bl] + b2r;
            float xh = innXC[32 + iu][bl] + b2h;
            float z  = 1.f / (1.f + expf(-(xz + rz)));
            float r  = 1.f / (1.f + expf(-(xr + rr)));
            float hh = tanhf(xh + r * rh);
            float hold = hl2[bl][swz512(ug)];
            float hnew = z * hold + (1.f - z) * hh;
            astore(hp2 + (size_t)(tc & 1) * BB * UU
                       + (size_t)(b0 + bl) * UU + ug, hnew);
            out2[((size_t)(b0 + bl) * TSEQ + tc) * UU + ug] = hnew;
            if (tc == TSEQ - 1) state2[(size_t)(b0 + bl) * UU + ug] = hnew;
        }
        __syncthreads();   // drains vmcnt: all h stores at MALL before flags

        if (tid == 0 && i < TSEQ)
            __hip_atomic_store(&aflags[g * GB + slot], i + 1,
                               __ATOMIC_RELAXED, __HIP_MEMORY_SCOPE_AGENT);
        if (tid == 512 && i >= 1)
            __hip_atomic_store(&cflags[g * GB + slot], i,
                               __ATOMIC_RELAXED, __HIP_MEMORY_SCOPE_AGENT);
    }
}

// ---------------------------------------------------------------------------
extern "C" void kernel_launch(void* const* d_in, const int* in_sizes, int n_in,
                              void* d_out, int out_size, void* d_ws, size_t ws_size,
                              hipStream_t stream)
{
    const float* x      = (const float*)d_in[0];
    const float* hidden = (const float*)d_in[1];
    const float* k1     = (const float*)d_in[2];
    const float* rk1    = (const float*)d_in[3];
    const float* b1     = (const float*)d_in[4];
    const float* k2     = (const float*)d_in[5];
    const float* rk2    = (const float*)d_in[6];
    const float* b2     = (const float*)d_in[7];

    const int M = BB * TSEQ;                      // 65536
    const size_t XPROJ_ELEMS = (size_t)M * NCOL;

    float* xp1    = (float*)d_ws;                         // M*NCOL
    float* h1ring = xp1 + XPROJ_ELEMS;                    // RING*BB*UU
    float* hp2    = h1ring + (size_t)RING * BB * UU;      // 2*BB*UU
    int*   aflags = (int*)(hp2 + 2 * (size_t)BB * UU);
    int*   cflags = aflags + 256;

    size_t need = (XPROJ_ELEMS + (size_t)(RING + 2) * BB * UU) * sizeof(float)
                + 512 * sizeof(int);
    if (ws_size < need) return;

    float* out2   = (float*)d_out;
    float* state1 = out2 + (size_t)BB * TSEQ * UU;
    float* state2 = state1 + BB * UU;

    hipMemsetAsync(aflags, 0, 512 * sizeof(int), stream);

    dim3 ggrid(NCOL / 64, M / 64);
    gemm_bias<<<ggrid, 256, 0, stream>>>(x, k1, b1, xp1, M, NCOL, 256);

    gru_fused<<<256, 1024, 0, stream>>>(xp1, hidden, rk1, b1, k2, rk2, b2,
                                        h1ring, hp2, aflags, cflags,
                                        out2, state1, state2);
}